// Round 16
// baseline (356.996 us; speedup 1.0000x reference)
//
#include <hip/hip_runtime.h>
#include <math.h>

#define DEV __device__ __forceinline__

DEV float lrelu(float v) { return fmaxf(v, 0.2f * v); }
DEV float4 ld4(const float* p) { return *reinterpret_cast<const float4*>(p); }

// ---------------- CSR build ----------------
__global__ void hist_kernel(const int* __restrict__ ei, int E, int* __restrict__ cnt) {
  int e = blockIdx.x * blockDim.x + threadIdx.x;
  if (e < E) atomicAdd(&cnt[ei[E + e]], 1);
}

__global__ __launch_bounds__(1024) void partial_kernel(const int* __restrict__ cnt, int N,
                                                       int* __restrict__ partials) {
  __shared__ int ws[16];
  int i = blockIdx.x * 1024 + threadIdx.x;
  int v = (i < N) ? cnt[i] : 0;
  #pragma unroll
  for (int off = 32; off >= 1; off >>= 1) v += __shfl_down(v, off);
  int lane = threadIdx.x & 63, wid = threadIdx.x >> 6;
  if (lane == 0) ws[wid] = v;
  __syncthreads();
  if (threadIdx.x < 64) {
    int t = (threadIdx.x < 16) ? ws[threadIdx.x] : 0;
    #pragma unroll
    for (int off = 8; off >= 1; off >>= 1) t += __shfl_down(t, off);
    if (threadIdx.x == 0) partials[blockIdx.x] = t;
  }
}

// cnt aliases cursor (each thread reads then writes only its own index) -> no __restrict__.
__global__ __launch_bounds__(1024) void apply_kernel(const int* cnt,
                                                     const int* __restrict__ partials,
                                                     int N, int* __restrict__ row_ptr,
                                                     int* cursor) {
  __shared__ int wsum[16];
  int off = 0;
  for (int i = 0; i < (int)blockIdx.x; ++i) off += partials[i];
  const int tid = threadIdx.x, lane = tid & 63, wid = tid >> 6;
  int i = blockIdx.x * 1024 + tid;
  int v = (i < N) ? cnt[i] : 0;
  int x = v;
  #pragma unroll
  for (int o = 1; o < 64; o <<= 1) {
    int y = __shfl_up(x, o);
    if (lane >= o) x += y;
  }
  if (lane == 63) wsum[wid] = x;
  __syncthreads();
  int woff = 0;
  for (int ww = 0; ww < wid; ++ww) woff += wsum[ww];
  int excl = off + woff + x - v;
  if (i < N) { row_ptr[i] = excl; cursor[i] = excl; }
  if (i == N - 1) row_ptr[N] = excl + v;
}

__global__ void scatter_kernel(const int* __restrict__ ei, int E,
                               int* __restrict__ cursor, int* __restrict__ csr_src) {
  int e = blockIdx.x * blockDim.x + threadIdx.x;
  if (e >= E) return;
  int s = ei[e], d = ei[E + e];
  int pos = atomicAdd(&cursor[d], 1);
  csr_src[pos] = s;
}

// ---------------- fused dual GEMM: Xl = A*Wl+bl, Xr = A*Wr+br ----------------
template <int K>
__global__ __launch_bounds__(256) void gemm_dual(
    const float* __restrict__ A, int N,
    const float* __restrict__ Wl, const float* __restrict__ bl,
    const float* __restrict__ Wr, const float* __restrict__ br,
    float* __restrict__ Xl, float* __restrict__ Xr) {
  constexpr int KC = 32;
  constexpr int BR = 128;
  constexpr int LDA = BR + 4;
  constexpr int LDW = 128 + 4;
  __shared__ float sA[KC][LDA];
  __shared__ float sW[KC][LDW];
  const int tid = threadIdx.x;
  const int rb = blockIdx.x * BR;
  const int rowg = tid >> 4;
  const int colg = tid & 15;
  float acc[8][8];
  #pragma unroll
  for (int i = 0; i < 8; ++i)
    #pragma unroll
    for (int j = 0; j < 8; ++j) acc[i][j] = 0.f;

  for (int kc = 0; kc < K; kc += KC) {
    #pragma unroll
    for (int rep = 0; rep < 4; ++rep) {
      int lin = rep * 1024 + tid * 4;
      int k = lin >> 7, j = lin & 127;
      const float* src = (j < 64) ? (Wl + (size_t)(kc + k) * 64 + j)
                                  : (Wr + (size_t)(kc + k) * 64 + (j - 64));
      *reinterpret_cast<float4*>(&sW[k][j]) = ld4(src);
    }
    #pragma unroll
    for (int rep = 0; rep < 4; ++rep) {
      int lin = rep * 1024 + tid * 4;
      int r = lin >> 5;
      int kk = lin & 31;
      int row = rb + r;
      if (row >= N) row = N - 1;
      float4 v = ld4(A + (size_t)row * K + kc + kk);
      sA[kk + 0][r] = v.x;
      sA[kk + 1][r] = v.y;
      sA[kk + 2][r] = v.z;
      sA[kk + 3][r] = v.w;
    }
    __syncthreads();
    #pragma unroll
    for (int k = 0; k < KC; ++k) {
      float a[8], wv[8];
      *reinterpret_cast<float4*>(&a[0]) = *reinterpret_cast<const float4*>(&sA[k][rowg * 8]);
      *reinterpret_cast<float4*>(&a[4]) = *reinterpret_cast<const float4*>(&sA[k][rowg * 8 + 4]);
      *reinterpret_cast<float4*>(&wv[0]) = *reinterpret_cast<const float4*>(&sW[k][colg * 8]);
      *reinterpret_cast<float4*>(&wv[4]) = *reinterpret_cast<const float4*>(&sW[k][colg * 8 + 4]);
      #pragma unroll
      for (int i = 0; i < 8; ++i)
        #pragma unroll
        for (int j = 0; j < 8; ++j) acc[i][j] = fmaf(a[i], wv[j], acc[i][j]);
    }
    __syncthreads();
  }
  const int cb = colg * 8;
  float bv[8];
  #pragma unroll
  for (int j = 0; j < 8; ++j) bv[j] = (cb < 64) ? bl[cb + j] : br[cb - 64 + j];
  #pragma unroll
  for (int i = 0; i < 8; ++i) {
    int row = rb + rowg * 8 + i;
    if (row < N) {
      float o[8];
      #pragma unroll
      for (int j = 0; j < 8; ++j) o[j] = acc[i][j] + bv[j];
      float* dst = (cb < 64) ? (Xl + (size_t)row * 64 + cb) : (Xr + (size_t)row * 64 + cb - 64);
      *reinterpret_cast<float4*>(dst) = make_float4(o[0], o[1], o[2], o[3]);
      *reinterpret_cast<float4*>(dst + 4) = make_float4(o[4], o[5], o[6], o[7]);
    }
  }
}

// ---------------- edge-batch building blocks ----------------
// load16: issue 16 independent gathers (32-bit element offsets -> saddr+voffset form)
DEV void load16(const float* __restrict__ xl, int sv, int c, float xv[16]) {
  #pragma unroll
  for (int j = 0; j < 16; ++j) {
    int sj = __shfl(sv, j);
    unsigned off = (unsigned)(sj * 64 + c);
    xv[j] = xl[off];
  }
}

// compute16: register-fold e-reduce + online softmax update + message accumulate.
// After the 4 fold rounds, lane l holds e_{l&15} reduced over its 16-lane group;
// FULL adds xor-16/32 rounds for the 64-lane (H=1) case.
template <bool FULL>
DEV void compute16(const float xv[16], float xrc, float attc, int c, int lim,
                   float& m, float& s, float& acc) {
  float u[16];
  #pragma unroll
  for (int j = 0; j < 16; ++j) {
    float t = xv[j] + xrc;
    u[j] = fmaxf(t, 0.2f * t) * attc;
  }
  // fold rounds: 16 -> 8 -> 4 -> 2 -> 1 values, reducing across lanes
  #pragma unroll
  for (int k = 0; k < 8; ++k) {
    float a = u[2 * k], b = u[2 * k + 1];
    float mine = (c & 1) ? b : a, oth = (c & 1) ? a : b;
    u[k] = mine + __shfl_xor(oth, 1);
  }
  #pragma unroll
  for (int k = 0; k < 4; ++k) {
    float a = u[2 * k], b = u[2 * k + 1];
    float mine = (c & 2) ? b : a, oth = (c & 2) ? a : b;
    u[k] = mine + __shfl_xor(oth, 2);
  }
  #pragma unroll
  for (int k = 0; k < 2; ++k) {
    float a = u[2 * k], b = u[2 * k + 1];
    float mine = (c & 4) ? b : a, oth = (c & 4) ? a : b;
    u[k] = mine + __shfl_xor(oth, 4);
  }
  {
    float a = u[0], b = u[1];
    float mine = (c & 8) ? b : a, oth = (c & 8) ? a : b;
    u[0] = mine + __shfl_xor(oth, 8);
  }
  float ej = u[0];
  if (FULL) { ej += __shfl_xor(ej, 16); ej += __shfl_xor(ej, 32); }

  const bool valid = (c & 15) < lim;
  float bm = valid ? ej : -INFINITY;
  bm = fmaxf(bm, __shfl_xor(bm, 1));
  bm = fmaxf(bm, __shfl_xor(bm, 2));
  bm = fmaxf(bm, __shfl_xor(bm, 4));
  bm = fmaxf(bm, __shfl_xor(bm, 8));
  float mn = fmaxf(m, bm);
  float sc = __expf(m - mn);
  s *= sc; acc *= sc; m = mn;

  float pj = valid ? __expf(ej - m) : 0.f;
  float ps = pj;
  ps += __shfl_xor(ps, 1);
  ps += __shfl_xor(ps, 2);
  ps += __shfl_xor(ps, 4);
  ps += __shfl_xor(ps, 8);
  s += ps;

  const int base = c & 48;
  #pragma unroll
  for (int j = 0; j < 16; ++j) {
    if (j < lim) {
      float p = __shfl(pj, base + j);
      acc = fmaf(p, xv[j], acc);
    }
  }
}

// drain one node's remaining batches (full + tail) single-stream
template <bool FULL>
DEV void run_node_single(const int* __restrict__ csr_src, const float* __restrict__ xl,
                         int p, int p1, float xrc, float attc, int c,
                         float& m, float& s, float& acc) {
  for (; p + 16 <= p1; p += 16) {
    int sv = csr_src[p + (c & 15)];
    float xv[16];
    load16(xl, sv, c, xv);
    compute16<FULL>(xv, xrc, attc, c, 16, m, s, acc);
  }
  if (p < p1) {
    const int lim = p1 - p;
    int l = p + (c & 15); if (l >= p1) l = p1 - 1;
    int sv = csr_src[l];
    float xv[16];
    load16(xl, sv, c, xv);
    compute16<FULL>(xv, xrc, attc, c, lim, m, s, acc);
  }
}

// self-edge init of the online-softmax state
template <bool FULL>
DEV void init_state(float xls, float xrc, float attc,
                    float& m, float& s, float& acc) {
  float t0 = xls + xrc;
  float t = fmaxf(t0, 0.2f * t0) * attc;
  t += __shfl_xor(t, 1); t += __shfl_xor(t, 2);
  t += __shfl_xor(t, 4); t += __shfl_xor(t, 8);
  if (FULL) { t += __shfl_xor(t, 16); t += __shfl_xor(t, 32); }
  m = t; s = 1.f; acc = xls;
}

// ---------------- conv1 fused (H=4): two nodes per wave, interleaved ----------------
__global__ __launch_bounds__(256) void fused1_kernel(
    const int* __restrict__ row_ptr, const int* __restrict__ csr_src, int N,
    const float* __restrict__ xl, const float* __restrict__ xr,
    const float* __restrict__ att, const float* __restrict__ bias,
    float* __restrict__ out) {
  const int wid = blockIdx.x * 4 + (threadIdx.x >> 6);
  const int nA = wid * 2;
  if (nA >= N) return;
  const int nB = nA + 1;
  const bool hasB = (nB < N);
  const int c = threadIdx.x & 63;
  const float attc = att[c];

  const float xrcA = xr[(size_t)nA * 64 + c];
  const float xlsA = xl[(size_t)nA * 64 + c];
  float mA, sA, accA;
  init_state<false>(xlsA, xrcA, attc, mA, sA, accA);
  int pA = row_ptr[nA];
  const int p1A = row_ptr[nA + 1];

  float xrcB = 0.f, xlsB = 0.f, mB = 0.f, sB = 1.f, accB = 0.f;
  int pB = 0, p1B = 0;
  if (hasB) {
    xrcB = xr[(size_t)nB * 64 + c];
    xlsB = xl[(size_t)nB * 64 + c];
    init_state<false>(xlsB, xrcB, attc, mB, sB, accB);
    pB = row_ptr[nB];
    p1B = row_ptr[nB + 1];
  }

  // interleaved main loop: B's gathers fly under A's compute
  while (pA + 16 <= p1A && hasB && pB + 16 <= p1B) {
    int svA = csr_src[pA + (c & 15)];
    int svB = csr_src[pB + (c & 15)];
    float xvA[16], xvB[16];
    load16(xl, svA, c, xvA);
    load16(xl, svB, c, xvB);
    compute16<false>(xvA, xrcA, attc, c, 16, mA, sA, accA);
    compute16<false>(xvB, xrcB, attc, c, 16, mB, sB, accB);
    pA += 16; pB += 16;
  }
  run_node_single<false>(csr_src, xl, pA, p1A, xrcA, attc, c, mA, sA, accA);
  if (hasB) run_node_single<false>(csr_src, xl, pB, p1B, xrcB, attc, c, mB, sB, accB);

  float vA = accA / sA + bias[c];
  out[(size_t)nA * 64 + c] = vA > 0.f ? vA : expm1f(vA);  // fused ELU
  if (hasB) {
    float vB = accB / sB + bias[c];
    out[(size_t)nB * 64 + c] = vB > 0.f ? vB : expm1f(vB);
  }
}

// ---------------- conv2 fused (H=1) + bias2 + final linear, two nodes per wave ----------------
__global__ __launch_bounds__(256) void fused2_kernel(
    const int* __restrict__ row_ptr, const int* __restrict__ csr_src, int N,
    const float* __restrict__ xl, const float* __restrict__ xr,
    const float* __restrict__ att, const float* __restrict__ bias,
    const float* __restrict__ Wlin, const float* __restrict__ blin,
    float* __restrict__ out) {
  const int wid = blockIdx.x * 4 + (threadIdx.x >> 6);
  const int nA = wid * 2;
  if (nA >= N) return;
  const int nB = nA + 1;
  const bool hasB = (nB < N);
  const int c = threadIdx.x & 63;
  const float attc = att[c];

  const float xrcA = xr[(size_t)nA * 64 + c];
  const float xlsA = xl[(size_t)nA * 64 + c];
  float mA, sA, accA;
  init_state<true>(xlsA, xrcA, attc, mA, sA, accA);
  int pA = row_ptr[nA];
  const int p1A = row_ptr[nA + 1];

  float xrcB = 0.f, xlsB = 0.f, mB = 0.f, sB = 1.f, accB = 0.f;
  int pB = 0, p1B = 0;
  if (hasB) {
    xrcB = xr[(size_t)nB * 64 + c];
    xlsB = xl[(size_t)nB * 64 + c];
    init_state<true>(xlsB, xrcB, attc, mB, sB, accB);
    pB = row_ptr[nB];
    p1B = row_ptr[nB + 1];
  }

  while (pA + 16 <= p1A && hasB && pB + 16 <= p1B) {
    int svA = csr_src[pA + (c & 15)];
    int svB = csr_src[pB + (c & 15)];
    float xvA[16], xvB[16];
    load16(xl, svA, c, xvA);
    load16(xl, svB, c, xvB);
    compute16<true>(xvA, xrcA, attc, c, 16, mA, sA, accA);
    compute16<true>(xvB, xrcB, attc, c, 16, mB, sB, accB);
    pA += 16; pB += 16;
  }
  run_node_single<true>(csr_src, xl, pA, p1A, xrcA, attc, c, mA, sA, accA);
  if (hasB) run_node_single<true>(csr_src, xl, pB, p1B, xrcB, attc, c, mB, sB, accB);

  float yA = (accA / sA + bias[c]) * Wlin[c];
  yA += __shfl_xor(yA, 1); yA += __shfl_xor(yA, 2); yA += __shfl_xor(yA, 4);
  yA += __shfl_xor(yA, 8); yA += __shfl_xor(yA, 16); yA += __shfl_xor(yA, 32);
  if (c == 0) out[nA] = yA + blin[0];
  if (hasB) {
    float yB = (accB / sB + bias[c]) * Wlin[c];
    yB += __shfl_xor(yB, 1); yB += __shfl_xor(yB, 2); yB += __shfl_xor(yB, 4);
    yB += __shfl_xor(yB, 8); yB += __shfl_xor(yB, 16); yB += __shfl_xor(yB, 32);
    if (c == 0) out[nB] = yB + blin[0];
  }
}

// ---------------- launch ----------------
extern "C" void kernel_launch(void* const* d_in, const int* in_sizes, int n_in,
                              void* d_out, int out_size, void* d_ws, size_t ws_size,
                              hipStream_t stream) {
  const float* x     = (const float*)d_in[0];
  const int*   ei    = (const int*)d_in[1];
  const float* W1l   = (const float*)d_in[2];
  const float* b1l   = (const float*)d_in[3];
  const float* W1r   = (const float*)d_in[4];
  const float* b1r   = (const float*)d_in[5];
  const float* att1  = (const float*)d_in[6];
  const float* bias1 = (const float*)d_in[7];
  const float* W2l   = (const float*)d_in[8];
  const float* b2l   = (const float*)d_in[9];
  const float* W2r   = (const float*)d_in[10];
  const float* b2r   = (const float*)d_in[11];
  const float* att2  = (const float*)d_in[12];
  const float* bias2 = (const float*)d_in[13];
  const float* Wlin  = (const float*)d_in[14];
  const float* blin  = (const float*)d_in[15];
  float* out = (float*)d_out;

  const int Fin = 128;
  const int N = in_sizes[0] / Fin;
  const int E = in_sizes[1] / 2;

  char* w = (char*)d_ws;
  auto alloc = [&](size_t bytes) {
    char* p = w;
    w += (bytes + 255) & ~(size_t)255;
    return p;
  };
  float* xl1 = (float*)alloc((size_t)N * 64 * 4);
  float* xr1 = (float*)alloc((size_t)N * 64 * 4);
  float* h1  = (float*)alloc((size_t)N * 64 * 4);
  int* row_ptr  = (int*)alloc((size_t)(N + 1) * 4);
  int* cursor   = (int*)alloc((size_t)N * 4);
  int* partials = (int*)alloc((size_t)256 * 4);
  int* csr_src  = (int*)alloc((size_t)E * 4);
  // conv2 reuses conv1 buffers
  float* xl2 = xl1; float* xr2 = xr1;

  const int tpb = 256;
  const int nscan = (N + 1023) / 1024;
  const int nfused = (N + 7) / 8;  // 2 nodes per wave, 4 waves per block

  // CSR build (reduce-then-scan)
  hipMemsetAsync(cursor, 0, (size_t)N * 4, stream);
  hist_kernel<<<(E + tpb - 1) / tpb, tpb, 0, stream>>>(ei, E, cursor);
  partial_kernel<<<nscan, 1024, 0, stream>>>(cursor, N, partials);
  apply_kernel<<<nscan, 1024, 0, stream>>>(cursor, partials, N, row_ptr, cursor);
  scatter_kernel<<<(E + tpb - 1) / tpb, tpb, 0, stream>>>(ei, E, cursor, csr_src);

  // conv1: dual GEMM + fused edge/softmax/aggregate (+ELU)
  gemm_dual<128><<<(N + 127) / 128, 256, 0, stream>>>(x, N, W1l, b1l, W1r, b1r, xl1, xr1);
  fused1_kernel<<<nfused, 256, 0, stream>>>(row_ptr, csr_src, N, xl1, xr1, att1, bias1, h1);

  // conv2: dual GEMM + fused (+final linear)
  gemm_dual<64><<<(N + 127) / 128, 256, 0, stream>>>(h1, N, W2l, b2l, W2r, b2r, xl2, xr2);
  fused2_kernel<<<nfused, 256, 0, stream>>>(row_ptr, csr_src, N, xl2, xr2, att2, bias2, Wlin, blin, out);
}